// Round 9
// baseline (786.791 us; speedup 1.0000x reference)
//
#include <hip/hip_runtime.h>

#define Tn 512
#define Hn 1024
#define Fn 64
#define NTH 256
#define NW (NTH / 64)

#define STEPB (12u * 256u * 16u) /* 49152 B per timestep of records */
#define MAXTOFF (511u * STEPB)
#define REC_PASS ((unsigned long long)Tn * STEPB) /* 24 MiB per pass */
#define YXE_OFF (2ull * REC_PASS)
#define WS_NEED (2ull * REC_PASS + 16ull * 512ull * 16ull)

typedef unsigned u32x4 __attribute__((ext_vector_type(4)));
typedef __fp16 h2 __attribute__((ext_vector_type(2)));

struct QParams {
  const float *x;
  const float *qw0, *qw1, *qw2, *qw3;
  const float *Wy_e, *by_e, *Wf_e, *bf_e, *Wi_e, *bi_e, *Wu_e, *bu_e, *Wo_e, *bo_e;
  const float *Wy_d, *by_d, *Wf_d, *bf_d, *Wi_d, *bi_d, *Wu_d, *bu_d, *Wo_d, *bo_d;
  const float *Wt, *bt;
  float *out;
};

// ---- sync / wait primitives -------------------------------------------------
#define BAR()                                                                  \
  do {                                                                         \
    asm volatile("s_waitcnt lgkmcnt(0)" ::: "memory");                         \
    __builtin_amdgcn_s_barrier();                                              \
    asm volatile("" ::: "memory");                                             \
  } while (0)
#define WAIT_VM(N)                                                             \
  do {                                                                         \
    asm volatile("s_waitcnt vmcnt(" #N ")" ::: "memory");                      \
    __builtin_amdgcn_sched_barrier(0);                                         \
  } while (0)

// ---- DPP / packed helpers ---------------------------------------------------
template <int CTRL, int RM, int BM, bool BC>
__device__ __forceinline__ float dppadd(float x) {
  int t = __builtin_amdgcn_update_dpp(0, __builtin_bit_cast(int, x), CTRL, RM,
                                      BM, BC);
  return x + __builtin_bit_cast(float, t);
}
template <int CTRL>
__device__ __forceinline__ float dppmov(float x) {
  int t = __builtin_amdgcn_update_dpp(0, __builtin_bit_cast(int, x), CTRL, 0xF,
                                      0xF, true);
  return __builtin_bit_cast(float, t);
}
__device__ __forceinline__ float wave_sum63(float x) {
  x = dppadd<0xB1, 0xF, 0xF, true>(x);
  x = dppadd<0x4E, 0xF, 0xF, true>(x);
  x = dppadd<0x141, 0xF, 0xF, true>(x);
  x = dppadd<0x140, 0xF, 0xF, true>(x);
  x = dppadd<0x142, 0xA, 0xF, false>(x);
  x = dppadd<0x143, 0xC, 0xF, false>(x);
  return x; // lane 63 = wave total
}
__device__ __forceinline__ float tanhc(float c) {
  float e = __builtin_amdgcn_exp2f(c * 2.885390081777927f);
  return fmaf(-2.f, __builtin_amdgcn_rcpf(e + 1.f), 1.f);
}
__device__ __forceinline__ h2 pk2(float a, float b) {
  return __builtin_amdgcn_cvt_pkrtz(a, b);
}
__device__ __forceinline__ h2 uh(unsigned u) { return __builtin_bit_cast(h2, u); }
__device__ __forceinline__ float fdot2f(h2 a, h2 b, float c) {
#if __has_builtin(__builtin_amdgcn_fdot2)
  return __builtin_amdgcn_fdot2(a, b, c, false);
#else
  float d;
  asm("v_dot2_f32_f16 %0, %1, %2, %3" : "=v"(d) : "v"(a), "v"(b), "v"(c));
  return d;
#endif
}
__device__ __forceinline__ unsigned pkh(float a, float b) { // RNE pack (prep)
  h2 h;
  h.x = (__fp16)a;
  h.y = (__fp16)b;
  return __builtin_bit_cast(unsigned, h);
}

struct LaneCtx {
  int tid, lane, wid;
  unsigned jt16;
  bool q1, q2;
  float w4lane;
  float mlane, alane, klane;
};
struct SBase {
  unsigned long long a[12];
};

// =============================================================================
// Pre-pass: f16 records, ws[pass][t][comp(12)][j(256)] u32x4, 4 elems/thread:
//   elem e of thread j = global index j + 256*e.
//   comps g*2+k (g=f,i,u,o; k=0,1): { h2(Wg[n0,n1][j+512k]), h2(Wg[n2,n3][j+512k]),
//                                     h2(Wg[n0,n1][j+512k+256]), h2(Wg[n2,n3][j+512k+256]) }
//   comp 8: biases elems0,1: { h2(bf[j],bf[j+256]), h2(bi..), h2(bu..), h2(bo..) }
//   comp 9: biases elems2,3 (j+512, j+768)
//   comp10: { h2(Wy[j][q],Wy[j+256][q]) q=0..3 } ; comp11: same for j+512,j+768
// Encoder also emits yx[b][t][4] f32 = x(b,t,:)@Wy_e[t,1024:,:] + by_e[t].
// =============================================================================
__global__ __launch_bounds__(256) void qprep_kernel(QParams p, char *ws) {
  int t = blockIdx.x;
  const bool dec = (t >= 512);
  if (dec) t -= 512;
  const int j = threadIdx.x;

  const float *Wg0 = dec ? p.Wf_d : p.Wf_e, *Wg1 = dec ? p.Wi_d : p.Wi_e;
  const float *Wg2 = dec ? p.Wu_d : p.Wu_e, *Wg3 = dec ? p.Wo_d : p.Wo_e;
  const float *bf = dec ? p.bf_d : p.bf_e, *bi = dec ? p.bi_d : p.bi_e;
  const float *bu = dec ? p.bu_d : p.bu_e, *bo = dec ? p.bo_d : p.bo_e;
  const float *Wy = dec ? p.Wy_d : p.Wy_e;
  const int K = dec ? (Hn + 1) : (Hn + Fn);

  char *base = ws + (dec ? REC_PASS : 0) + (size_t)t * STEPB;
  const int t4 = t * 4096;
  const float *Wg[4] = {Wg0, Wg1, Wg2, Wg3};
#pragma unroll
  for (int g = 0; g < 4; ++g) {
#pragma unroll
    for (int k = 0; k < 2; ++k) {
      const int jb = j + 512 * k;
      u32x4 v;
      v.x = pkh(Wg[g][t4 + 0 * 1024 + jb], Wg[g][t4 + 1 * 1024 + jb]);
      v.y = pkh(Wg[g][t4 + 2 * 1024 + jb], Wg[g][t4 + 3 * 1024 + jb]);
      v.z = pkh(Wg[g][t4 + 0 * 1024 + jb + 256], Wg[g][t4 + 1 * 1024 + jb + 256]);
      v.w = pkh(Wg[g][t4 + 2 * 1024 + jb + 256], Wg[g][t4 + 3 * 1024 + jb + 256]);
      *(u32x4 *)(base + (g * 2 + k) * 4096 + j * 16) = v;
    }
  }
  {
    const int tb = t * 1024;
#pragma unroll
    for (int k = 0; k < 2; ++k) {
      const int jb = tb + j + 512 * k;
      u32x4 v = {pkh(bf[jb], bf[jb + 256]), pkh(bi[jb], bi[jb + 256]),
                 pkh(bu[jb], bu[jb + 256]), pkh(bo[jb], bo[jb + 256])};
      *(u32x4 *)(base + (8 + k) * 4096 + j * 16) = v;
    }
  }
  {
#pragma unroll
    for (int k = 0; k < 2; ++k) {
      const int jb = j + 512 * k;
      const float4 w0 = *(const float4 *)(Wy + ((size_t)t * K + jb) * 4);
      const float4 w1 = *(const float4 *)(Wy + ((size_t)t * K + jb + 256) * 4);
      u32x4 v = {pkh(w0.x, w1.x), pkh(w0.y, w1.y), pkh(w0.z, w1.z),
                 pkh(w0.w, w1.w)};
      *(u32x4 *)(base + (10 + k) * 4096 + j * 16) = v;
    }
  }

  if (!dec && j < 16) { // yx[b][t] = x(b,t,:)@Wy_e[t,1024:,:] + by_e[t]
    const int b = j;
    float a0 = p.by_e[t * 4 + 0], a1 = p.by_e[t * 4 + 1],
          a2 = p.by_e[t * 4 + 2], a3 = p.by_e[t * 4 + 3];
#pragma unroll 8
    for (int k = 0; k < 64; ++k) {
      const float xv = p.x[((size_t)b * Tn + t) * Fn + k];
      const float4 wr =
          *(const float4 *)(p.Wy_e + ((size_t)t * (Hn + Fn) + Hn + k) * 4);
      a0 = fmaf(xv, wr.x, a0);
      a1 = fmaf(xv, wr.y, a1);
      a2 = fmaf(xv, wr.z, a2);
      a3 = fmaf(xv, wr.w, a3);
    }
    ((float4 *)(ws + YXE_OFF))[(size_t)b * Tn + t] =
        make_float4(a0, a1, a2, a3);
  }
}

// =============================================================================
// Main f16 scan kernel: 256 threads, 4 elems/thread, 4-deep pipeline
// =============================================================================
struct Regs {
  u32x4 g0, g1, g2, g3, g4, g5, g6, g7; // gates f,i,u,o × elem-halves
  u32x4 b8, b9;                         // biases
  u32x4 w10, w11;                       // wy pairs
};

__device__ __forceinline__ void issue_pf(Regs &r, const SBase &sb,
                                         unsigned voff) {
  asm volatile("global_load_dwordx4 %0, %1, %2" : "=v"(r.w10) : "v"(voff), "s"(sb.a[10]));
  asm volatile("global_load_dwordx4 %0, %1, %2" : "=v"(r.w11) : "v"(voff), "s"(sb.a[11]));
  asm volatile("global_load_dwordx4 %0, %1, %2" : "=v"(r.g0) : "v"(voff), "s"(sb.a[0]));
  asm volatile("global_load_dwordx4 %0, %1, %2" : "=v"(r.g1) : "v"(voff), "s"(sb.a[1]));
  asm volatile("global_load_dwordx4 %0, %1, %2" : "=v"(r.g2) : "v"(voff), "s"(sb.a[2]));
  asm volatile("global_load_dwordx4 %0, %1, %2" : "=v"(r.g3) : "v"(voff), "s"(sb.a[3]));
  asm volatile("global_load_dwordx4 %0, %1, %2" : "=v"(r.g4) : "v"(voff), "s"(sb.a[4]));
  asm volatile("global_load_dwordx4 %0, %1, %2" : "=v"(r.g5) : "v"(voff), "s"(sb.a[5]));
  asm volatile("global_load_dwordx4 %0, %1, %2" : "=v"(r.g6) : "v"(voff), "s"(sb.a[6]));
  asm volatile("global_load_dwordx4 %0, %1, %2" : "=v"(r.g7) : "v"(voff), "s"(sb.a[7]));
  asm volatile("global_load_dwordx4 %0, %1, %2" : "=v"(r.b8) : "v"(voff), "s"(sb.a[8]));
  asm volatile("global_load_dwordx4 %0, %1, %2" : "=v"(r.b9) : "v"(voff), "s"(sb.a[9]));
}

template <int PAR>
__device__ __forceinline__ void
qstep(int t, Regs &r, unsigned &toff, const SBase &sb, const LaneCtx &L,
      float *red_t, const float *yxby_l, float &h0, float &h1, float &h2r,
      float &h3, float &c0, float &c1, float &c2r, float &c3, h2 &hp0,
      h2 &hp1) {
  const float yxs = yxby_l[t * 4 + (L.lane & 3)];
  WAIT_VM(36); // this step's 12 loads landed; 36 (3 steps) still in flight
  // ---------- phase A: y partials via dot2, DPP wave reduce
  float a0 = fdot2f(hp0, uh(r.w10.x), 0.f);
  float a1 = fdot2f(hp0, uh(r.w10.y), 0.f);
  float a2 = fdot2f(hp0, uh(r.w10.z), 0.f);
  float a3 = fdot2f(hp0, uh(r.w10.w), 0.f);
  a0 = fdot2f(hp1, uh(r.w11.x), a0);
  a1 = fdot2f(hp1, uh(r.w11.y), a1);
  a2 = fdot2f(hp1, uh(r.w11.z), a2);
  a3 = fdot2f(hp1, uh(r.w11.w), a3);
  a0 = wave_sum63(a0);
  a1 = wave_sum63(a1);
  a2 = wave_sum63(a2);
  a3 = wave_sum63(a3);
  if (L.lane == 63) {
    red_t[PAR * 16 + 0 * 4 + L.wid] = a0;
    red_t[PAR * 16 + 1 * 4 + L.wid] = a1;
    red_t[PAR * 16 + 2 * 4 + L.wid] = a2;
    red_t[PAR * 16 + 3 * 4 + L.wid] = a3;
  }
  BAR();
  // ---------- phase B: lane sums ONLY its own component q = lane&3
  const float4 rA = *(const float4 *)&red_t[PAR * 16 + (L.lane & 3) * 4];
  const float yq = (rA.x + rA.y) + (rA.z + rA.w);
  const float ang = yq + yxs + L.w4lane;
  const float cc = __cosf(ang);
  const float t1 = dppmov<0xB1>(cc);
  const float d1 = cc * t1;
  const float t2 = dppmov<0x4E>(d1);
  const float d2 = d1 * t2;
  const float zu = t1 * t2;
  const float zv = cc * t2;
  const float z = L.q2 ? (L.q1 ? d2 : zv) : (L.q1 ? d1 : zu);
  const float s =
      __builtin_amdgcn_rcpf(1.f + __builtin_amdgcn_exp2f(L.klane * z));
  const float act = fmaf(s, L.mlane, L.alane);
  const float actn = dppmov<0xB1>(act);
  const unsigned apk = __builtin_bit_cast(unsigned, pk2(act, actn));
  const h2 F01 = uh((unsigned)__builtin_amdgcn_readlane(apk, 0));
  const h2 F23 = uh((unsigned)__builtin_amdgcn_readlane(apk, 2));
  const h2 I01 = uh((unsigned)__builtin_amdgcn_readlane(apk, 4));
  const h2 I23 = uh((unsigned)__builtin_amdgcn_readlane(apk, 6));
  const h2 U01 = uh((unsigned)__builtin_amdgcn_readlane(apk, 8));
  const h2 U23 = uh((unsigned)__builtin_amdgcn_readlane(apk, 10));
  const h2 O01 = uh((unsigned)__builtin_amdgcn_readlane(apk, 12));
  const h2 O23 = uh((unsigned)__builtin_amdgcn_readlane(apk, 14));
  // ---------- phase C: gate dot2 matvecs, 4 elems
  const h2 bF01 = uh(r.b8.x), bI01 = uh(r.b8.y), bU01 = uh(r.b8.z),
           bO01 = uh(r.b8.w);
  const h2 bF23 = uh(r.b9.x), bI23 = uh(r.b9.y), bU23 = uh(r.b9.z),
           bO23 = uh(r.b9.w);
  // elem 0,1 from g0,g2,g4,g6 ; elem 2,3 from g1,g3,g5,g7
  const float fv0 = fdot2f(F01, uh(r.g0.x), fdot2f(F23, uh(r.g0.y), (float)bF01.x));
  const float fv1 = fdot2f(F01, uh(r.g0.z), fdot2f(F23, uh(r.g0.w), (float)bF01.y));
  const float fv2 = fdot2f(F01, uh(r.g1.x), fdot2f(F23, uh(r.g1.y), (float)bF23.x));
  const float fv3 = fdot2f(F01, uh(r.g1.z), fdot2f(F23, uh(r.g1.w), (float)bF23.y));
  const float iv0 = fdot2f(I01, uh(r.g2.x), fdot2f(I23, uh(r.g2.y), (float)bI01.x));
  const float iv1 = fdot2f(I01, uh(r.g2.z), fdot2f(I23, uh(r.g2.w), (float)bI01.y));
  const float iv2 = fdot2f(I01, uh(r.g3.x), fdot2f(I23, uh(r.g3.y), (float)bI23.x));
  const float iv3 = fdot2f(I01, uh(r.g3.z), fdot2f(I23, uh(r.g3.w), (float)bI23.y));
  const float uv0 = fdot2f(U01, uh(r.g4.x), fdot2f(U23, uh(r.g4.y), (float)bU01.x));
  const float uv1 = fdot2f(U01, uh(r.g4.z), fdot2f(U23, uh(r.g4.w), (float)bU01.y));
  const float uv2 = fdot2f(U01, uh(r.g5.x), fdot2f(U23, uh(r.g5.y), (float)bU23.x));
  const float uv3 = fdot2f(U01, uh(r.g5.z), fdot2f(U23, uh(r.g5.w), (float)bU23.y));
  const float ov0 = fdot2f(O01, uh(r.g6.x), fdot2f(O23, uh(r.g6.y), (float)bO01.x));
  const float ov1 = fdot2f(O01, uh(r.g6.z), fdot2f(O23, uh(r.g6.w), (float)bO01.y));
  const float ov2 = fdot2f(O01, uh(r.g7.x), fdot2f(O23, uh(r.g7.y), (float)bO23.x));
  const float ov3 = fdot2f(O01, uh(r.g7.z), fdot2f(O23, uh(r.g7.w), (float)bO23.y));
  c0 = fmaf(fv0, c0, iv0 * uv0);
  h0 = ov0 * tanhc(c0);
  c1 = fmaf(fv1, c1, iv1 * uv1);
  h1 = ov1 * tanhc(c1);
  c2r = fmaf(fv2, c2r, iv2 * uv2);
  h2r = ov2 * tanhc(c2r);
  c3 = fmaf(fv3, c3, iv3 * uv3);
  h3 = ov3 * tanhc(c3);
  hp0 = pk2(h0, h1);
  hp1 = pk2(h2r, h3);
  // ---------- reissue this buffer for t+4 (clamped at the tail)
  issue_pf(r, sb, L.jt16 + toff);
  toff = toff + STEPB;
  if (toff > MAXTOFF) toff = MAXTOFF;
}

__device__ __forceinline__ void run_pass(const SBase &sb, const LaneCtx &L,
                                         float *red_t, const float *yxby_l,
                                         float &h0, float &h1, float &h2r,
                                         float &h3, float &c0, float &c1,
                                         float &c2r, float &c3) {
  Regs R0, R1, R2, R3;
  WAIT_VM(0);
  issue_pf(R0, sb, L.jt16 + 0 * STEPB);
  issue_pf(R1, sb, L.jt16 + 1 * STEPB);
  issue_pf(R2, sb, L.jt16 + 2 * STEPB);
  issue_pf(R3, sb, L.jt16 + 3 * STEPB);
  unsigned toff = 4 * STEPB;
  h2 hp0 = pk2(0.f, 0.f), hp1 = pk2(0.f, 0.f);
  for (int t = 0; t < Tn; t += 4) {
    qstep<0>(t + 0, R0, toff, sb, L, red_t, yxby_l, h0, h1, h2r, h3, c0, c1, c2r, c3, hp0, hp1);
    qstep<1>(t + 1, R1, toff, sb, L, red_t, yxby_l, h0, h1, h2r, h3, c0, c1, c2r, c3, hp0, hp1);
    qstep<0>(t + 2, R2, toff, sb, L, red_t, yxby_l, h0, h1, h2r, h3, c0, c1, c2r, c3, hp0, hp1);
    qstep<1>(t + 3, R3, toff, sb, L, red_t, yxby_l, h0, h1, h2r, h3, c0, c1, c2r, c3, hp0, hp1);
  }
  asm volatile("s_waitcnt vmcnt(0)" ::: "memory");
  __builtin_amdgcn_sched_barrier(0);
}

__global__ __launch_bounds__(NTH, 1) void qlstm_f16_kernel(QParams p,
                                                           char *ws) {
  const int b = blockIdx.x;
  LaneCtx L;
  L.tid = threadIdx.x;
  L.lane = L.tid & 63;
  L.wid = L.tid >> 6;
  L.jt16 = (unsigned)L.tid * 16u;
  const int q = L.lane & 3, g = (L.lane >> 2) & 3;
  L.q1 = q & 1;
  L.q2 = q & 2;
  {
    const float *qwp =
        (g == 0) ? p.qw0 : (g == 1) ? p.qw1 : (g == 2) ? p.qw2 : p.qw3;
    L.w4lane = qwp[q];
  }
  L.mlane = (g == 2) ? 2.f : 1.f;
  L.alane = 1.f - L.mlane;
  L.klane = -L.mlane * 1.4426950408889634f;

  __shared__ __align__(16) float red_t[2 * 4 * NW];
  __shared__ __align__(16) float yxby_l[Tn * 4];
  __shared__ __align__(16) float hbuf[Hn];

  SBase sbE, sbD;
#pragma unroll
  for (int k = 0; k < 12; ++k) {
    sbE.a[k] = (unsigned long long)ws + (unsigned long long)k * 4096ull;
    sbD.a[k] = (unsigned long long)ws + REC_PASS + (unsigned long long)k * 4096ull;
  }

  // ---- encoder prologue: stage yx(+by) table (512 float4 over 256 threads)
#pragma unroll
  for (int i = 0; i < 2; ++i)
    ((float4 *)yxby_l)[L.tid + i * NTH] =
        ((const float4 *)(ws + YXE_OFF))[(size_t)b * Tn + L.tid + i * NTH];
  float h0 = 0.f, h1 = 0.f, h2r = 0.f, h3 = 0.f;
  float c0 = 0.f, c1 = 0.f, c2r = 0.f, c3 = 0.f;
  __syncthreads();

  run_pass(sbE, L, red_t, yxby_l, h0, h1, h2r, h3, c0, c1, c2r, c3);

  // ---- transition: stage h_enc, build decoder yx table
  __syncthreads();
  hbuf[L.tid] = h0;
  hbuf[L.tid + 256] = h1;
  hbuf[L.tid + 512] = h2r;
  hbuf[L.tid + 768] = h3;
  __syncthreads();
#pragma unroll
  for (int i = 0; i < 2; ++i) {
    const int t2 = L.tid + i * NTH; // t2 < 512 = Tn
    const float hv = hbuf[t2];      // = h_enc[t2]
    const float4 wx =
        *(const float4 *)(p.Wy_d + ((size_t)t2 * (Hn + 1) + Hn) * 4);
    const float4 bd = *(const float4 *)(p.by_d + t2 * 4);
    ((float4 *)yxby_l)[t2] =
        make_float4(fmaf(hv, wx.x, bd.x), fmaf(hv, wx.y, bd.y),
                    fmaf(hv, wx.z, bd.z), fmaf(hv, wx.w, bd.w));
  }
  h0 = h1 = h2r = h3 = 0.f;
  c0 = c1 = c2r = c3 = 0.f;
  __syncthreads();

  run_pass(sbD, L, red_t, yxby_l, h0, h1, h2r, h3, c0, c1, c2r, c3);

  // ---- projection: out[b][t] = h_dec @ Wt[:,t] + bt[t]
  __syncthreads();
  hbuf[L.tid] = h0;
  hbuf[L.tid + 256] = h1;
  hbuf[L.tid + 512] = h2r;
  hbuf[L.tid + 768] = h3;
  __syncthreads();
#pragma unroll
  for (int i = 0; i < 2; ++i) {
    const int t2 = L.tid + i * NTH;
    float acc = p.bt[t2];
    const float4 *h4 = (const float4 *)hbuf;
#pragma unroll 4
    for (int j4 = 0; j4 < Hn / 4; ++j4) {
      const float4 hv = h4[j4];
      acc = fmaf(hv.x, p.Wt[(j4 * 4 + 0) * Tn + t2], acc);
      acc = fmaf(hv.y, p.Wt[(j4 * 4 + 1) * Tn + t2], acc);
      acc = fmaf(hv.z, p.Wt[(j4 * 4 + 2) * Tn + t2], acc);
      acc = fmaf(hv.w, p.Wt[(j4 * 4 + 3) * Tn + t2], acc);
    }
    p.out[(size_t)b * Tn + t2] = acc;
  }
}

// =============================================================================
// Fallback (round-3 f32 kernel, 512 threads): used only if ws_size < WS_NEED.
// =============================================================================
#define FNTH 512
#define FNW (FNTH / 64)
__device__ __forceinline__ float sum8_all(float x) {
  x = dppadd<0xB1, 0xF, 0xF, true>(x);
  x = dppadd<0x4E, 0xF, 0xF, true>(x);
  x = dppadd<0x141, 0xF, 0xF, true>(x);
  return x;
}

struct WB {
  float w[32];
  float bb[8];
  float4 wy0, wy1;
  float4 wyx;
  float xv;
};

template <bool DEC>
__device__ __forceinline__ WB
pf_fb(int t, int b, int tid, const float *__restrict__ x,
      const float *__restrict__ Wy, const float *__restrict__ Wf,
      const float *__restrict__ bfp, const float *__restrict__ Wi,
      const float *__restrict__ bip, const float *__restrict__ Wu,
      const float *__restrict__ bup, const float *__restrict__ Wo,
      const float *__restrict__ bop) {
  WB d;
  const int K = DEC ? (Hn + 1) : (Hn + Fn);
  const int g0 = t * 4096 + tid;
#pragma unroll
  for (int e = 0; e < 2; ++e) {
    const int ge = g0 + e * 512;
#pragma unroll
    for (int n = 0; n < 4; ++n) {
      d.w[e * 16 + 0 * 4 + n] = Wf[ge + n * 1024];
      d.w[e * 16 + 1 * 4 + n] = Wi[ge + n * 1024];
      d.w[e * 16 + 2 * 4 + n] = Wu[ge + n * 1024];
      d.w[e * 16 + 3 * 4 + n] = Wo[ge + n * 1024];
    }
    const int be = t * 1024 + tid + e * 512;
    d.bb[e * 4 + 0] = bfp[be];
    d.bb[e * 4 + 1] = bip[be];
    d.bb[e * 4 + 2] = bup[be];
    d.bb[e * 4 + 3] = bop[be];
  }
  d.wy0 = *(const float4 *)(Wy + (t * K + tid) * 4);
  d.wy1 = *(const float4 *)(Wy + (t * K + tid + 512) * 4);
  if (!DEC) {
    if (tid < Fn) {
      d.wyx = *(const float4 *)(Wy + (t * K + Hn + tid) * 4);
      d.xv = x[(b * Tn + t) * Fn + tid];
    }
  } else {
    if (tid == 0) d.wyx = *(const float4 *)(Wy + (t * K + Hn) * 4);
  }
  return d;
}

struct FLane {
  int tid, lane, wid;
  bool q1, q2;
  float w4lane, mlane, alane, klane;
};

template <bool DEC, int PAR>
__device__ __forceinline__ void
step_fb(int t, int tn, const WB &rd, WB &wr, int b, const FLane &L,
        const float *__restrict__ x, const float *__restrict__ Wy,
        const float *__restrict__ Wf, const float *__restrict__ bfp,
        const float *__restrict__ Wi, const float *__restrict__ bip,
        const float *__restrict__ Wu, const float *__restrict__ bup,
        const float *__restrict__ Wo, const float *__restrict__ bop,
        float4 (*red4)[FNW], const float *by_l, const float *henc_s, float &h0,
        float &h1, float &c0, float &c1) {
  float a0 = h0 * rd.wy0.x, a1 = h0 * rd.wy0.y, a2 = h0 * rd.wy0.z,
        a3 = h0 * rd.wy0.w;
  a0 = fmaf(h1, rd.wy1.x, a0);
  a1 = fmaf(h1, rd.wy1.y, a1);
  a2 = fmaf(h1, rd.wy1.z, a2);
  a3 = fmaf(h1, rd.wy1.w, a3);
  if (!DEC) {
    if (L.tid < Fn) {
      a0 = fmaf(rd.xv, rd.wyx.x, a0);
      a1 = fmaf(rd.xv, rd.wyx.y, a1);
      a2 = fmaf(rd.xv, rd.wyx.z, a2);
      a3 = fmaf(rd.xv, rd.wyx.w, a3);
    }
  } else {
    if (L.tid == 0) {
      const float xv = henc_s[t];
      a0 = fmaf(xv, rd.wyx.x, a0);
      a1 = fmaf(xv, rd.wyx.y, a1);
      a2 = fmaf(xv, rd.wyx.z, a2);
      a3 = fmaf(xv, rd.wyx.w, a3);
    }
  }
  a0 = wave_sum63(a0);
  a1 = wave_sum63(a1);
  a2 = wave_sum63(a2);
  a3 = wave_sum63(a3);
  if (L.lane == 63) red4[PAR][L.wid] = make_float4(a0, a1, a2, a3);
  wr = pf_fb<DEC>(tn, b, L.tid, x, Wy, Wf, bfp, Wi, bip, Wu, bup, Wo, bop);
  BAR();
  float4 rv = red4[PAR][L.lane & 7];
  const float byq = by_l[t * 4 + (L.lane & 3)];
  float y0 = sum8_all(rv.x), y1 = sum8_all(rv.y), y2 = sum8_all(rv.z),
        y3 = sum8_all(rv.w);
  const float yq = L.q2 ? (L.q1 ? y3 : y2) : (L.q1 ? y1 : y0);
  const float ang = yq + byq + L.w4lane;
  const float cc = __cosf(ang);
  const float t1 = dppmov<0xB1>(cc);
  const float d1 = cc * t1;
  const float t2 = dppmov<0x4E>(d1);
  const float d2 = d1 * t2;
  const float zu = t1 * t2;
  const float zv = cc * t2;
  const float z = L.q2 ? (L.q1 ? d2 : zv) : (L.q1 ? d1 : zu);
  const float s =
      __builtin_amdgcn_rcpf(1.f + __builtin_amdgcn_exp2f(L.klane * z));
  const float act = fmaf(s, L.mlane, L.alane);
#define RL(n)                                                                  \
  __builtin_bit_cast(float,                                                    \
                     __builtin_amdgcn_readlane(__builtin_bit_cast(int, act), n))
  const float f0 = RL(0), f1 = RL(1), f2 = RL(2), f3 = RL(3);
  const float i0 = RL(4), i1 = RL(5), i2 = RL(6), i3 = RL(7);
  const float u0 = RL(8), u1 = RL(9), u2 = RL(10), u3 = RL(11);
  const float o0 = RL(12), o1 = RL(13), o2 = RL(14), o3 = RL(15);
#undef RL
#pragma unroll
  for (int e = 0; e < 2; ++e) {
    float fv = rd.bb[e * 4 + 0], iv = rd.bb[e * 4 + 1], uv = rd.bb[e * 4 + 2],
          ov = rd.bb[e * 4 + 3];
    fv = fmaf(f0, rd.w[e * 16 + 0], fv);
    fv = fmaf(f1, rd.w[e * 16 + 1], fv);
    fv = fmaf(f2, rd.w[e * 16 + 2], fv);
    fv = fmaf(f3, rd.w[e * 16 + 3], fv);
    iv = fmaf(i0, rd.w[e * 16 + 4], iv);
    iv = fmaf(i1, rd.w[e * 16 + 5], iv);
    iv = fmaf(i2, rd.w[e * 16 + 6], iv);
    iv = fmaf(i3, rd.w[e * 16 + 7], iv);
    uv = fmaf(u0, rd.w[e * 16 + 8], uv);
    uv = fmaf(u1, rd.w[e * 16 + 9], uv);
    uv = fmaf(u2, rd.w[e * 16 + 10], uv);
    uv = fmaf(u3, rd.w[e * 16 + 11], uv);
    ov = fmaf(o0, rd.w[e * 16 + 12], ov);
    ov = fmaf(o1, rd.w[e * 16 + 13], ov);
    ov = fmaf(o2, rd.w[e * 16 + 14], ov);
    ov = fmaf(o3, rd.w[e * 16 + 15], ov);
    float &cr = e ? c1 : c0;
    float &hr = e ? h1 : h0;
    const float cn = fmaf(fv, cr, iv * uv);
    cr = cn;
    hr = ov * tanhc(cn);
  }
}

template <bool DEC>
__device__ void lstm_pass_fb(int b, const FLane &L,
                             const float *__restrict__ x,
                             const float *__restrict__ Wy,
                             const float *__restrict__ by,
                             const float *__restrict__ Wf,
                             const float *__restrict__ bfp,
                             const float *__restrict__ Wi,
                             const float *__restrict__ bip,
                             const float *__restrict__ Wu,
                             const float *__restrict__ bup,
                             const float *__restrict__ Wo,
                             const float *__restrict__ bop,
                             float4 (*red4)[FNW], float *by_l,
                             const float *henc_s, float &h0, float &h1,
                             float &c0, float &c1) {
#pragma unroll
  for (int i = 0; i < (Tn * 4) / FNTH; ++i)
    by_l[L.tid + i * FNTH] = by[L.tid + i * FNTH];
  __syncthreads();
  WB bufA = pf_fb<DEC>(0, b, L.tid, x, Wy, Wf, bfp, Wi, bip, Wu, bup, Wo, bop);
  WB bufB;
  for (int t = 0; t < Tn; t += 2) {
    step_fb<DEC, 0>(t, t + 1, bufA, bufB, b, L, x, Wy, Wf, bfp, Wi, bip, Wu,
                    bup, Wo, bop, red4, by_l, henc_s, h0, h1, c0, c1);
    step_fb<DEC, 1>(t + 1, (t + 2 < Tn) ? (t + 2) : (Tn - 1), bufB, bufA, b, L,
                    x, Wy, Wf, bfp, Wi, bip, Wu, bup, Wo, bop, red4, by_l,
                    henc_s, h0, h1, c0, c1);
  }
}

__global__ __launch_bounds__(FNTH, 2) void qlstm_fb_kernel(QParams p) {
  const int b = blockIdx.x;
  FLane L;
  L.tid = threadIdx.x;
  L.lane = L.tid & 63;
  L.wid = L.tid >> 6;
  const int q = L.lane & 3, g = (L.lane >> 2) & 3;
  L.q1 = q & 1;
  L.q2 = q & 2;
  {
    const float *qwp =
        (g == 0) ? p.qw0 : (g == 1) ? p.qw1 : (g == 2) ? p.qw2 : p.qw3;
    L.w4lane = qwp[q];
  }
  L.mlane = (g == 2) ? 2.f : 1.f;
  L.alane = 1.f - L.mlane;
  L.klane = -L.mlane * 1.4426950408889634f;

  __shared__ float4 red4[2][FNW];
  __shared__ float by_l[Tn * 4];
  __shared__ float henc_s[Hn];
  __shared__ float hst[Hn];

  float h0 = 0.f, h1 = 0.f, c0 = 0.f, c1 = 0.f;

  lstm_pass_fb<false>(b, L, p.x, p.Wy_e, p.by_e, p.Wf_e, p.bf_e, p.Wi_e,
                      p.bi_e, p.Wu_e, p.bu_e, p.Wo_e, p.bo_e, red4, by_l,
                      henc_s, h0, h1, c0, c1);
  henc_s[L.tid] = h0;
  henc_s[L.tid + FNTH] = h1;
  h0 = h1 = c0 = c1 = 0.f;
  __syncthreads();
  lstm_pass_fb<true>(b, L, nullptr, p.Wy_d, p.by_d, p.Wf_d, p.bf_d, p.Wi_d,
                     p.bi_d, p.Wu_d, p.bu_d, p.Wo_d, p.bo_d, red4, by_l,
                     henc_s, h0, h1, c0, c1);
  hst[L.tid] = h0;
  hst[L.tid + FNTH] = h1;
  __syncthreads();
  {
    float acc = p.bt[L.tid];
    const float4 *h4 = (const float4 *)hst;
#pragma unroll 4
    for (int j4 = 0; j4 < Hn / 4; ++j4) {
      const float4 hv = h4[j4];
      acc = fmaf(hv.x, p.Wt[(j4 * 4 + 0) * Tn + L.tid], acc);
      acc = fmaf(hv.y, p.Wt[(j4 * 4 + 1) * Tn + L.tid], acc);
      acc = fmaf(hv.z, p.Wt[(j4 * 4 + 2) * Tn + L.tid], acc);
      acc = fmaf(hv.w, p.Wt[(j4 * 4 + 3) * Tn + L.tid], acc);
    }
    p.out[(size_t)b * Tn + L.tid] = acc;
  }
}

extern "C" void kernel_launch(void *const *d_in, const int *in_sizes, int n_in,
                              void *d_out, int out_size, void *d_ws,
                              size_t ws_size, hipStream_t stream) {
  QParams p;
  p.x = (const float *)d_in[0];
  p.qw0 = (const float *)d_in[1];
  p.qw1 = (const float *)d_in[2];
  p.qw2 = (const float *)d_in[3];
  p.qw3 = (const float *)d_in[4];
  p.Wy_e = (const float *)d_in[5];
  p.by_e = (const float *)d_in[6];
  p.Wf_e = (const float *)d_in[7];
  p.bf_e = (const float *)d_in[8];
  p.Wi_e = (const float *)d_in[9];
  p.bi_e = (const float *)d_in[10];
  p.Wu_e = (const float *)d_in[11];
  p.bu_e = (const float *)d_in[12];
  p.Wo_e = (const float *)d_in[13];
  p.bo_e = (const float *)d_in[14];
  p.Wy_d = (const float *)d_in[15];
  p.by_d = (const float *)d_in[16];
  p.Wf_d = (const float *)d_in[17];
  p.bf_d = (const float *)d_in[18];
  p.Wi_d = (const float *)d_in[19];
  p.bi_d = (const float *)d_in[20];
  p.Wu_d = (const float *)d_in[21];
  p.bu_d = (const float *)d_in[22];
  p.Wo_d = (const float *)d_in[23];
  p.bo_d = (const float *)d_in[24];
  p.Wt = (const float *)d_in[25];
  p.bt = (const float *)d_in[26];
  p.out = (float *)d_out;

  if (ws_size >= WS_NEED) {
    char *ws = (char *)d_ws;
    hipLaunchKernelGGL(qprep_kernel, dim3(1024), dim3(256), 0, stream, p, ws);
    hipLaunchKernelGGL(qlstm_f16_kernel, dim3(16), dim3(NTH), 0, stream, p,
                       ws);
  } else {
    hipLaunchKernelGGL(qlstm_fb_kernel, dim3(16), dim3(FNTH), 0, stream, p);
  }
}

// Round 10
// 659.761 us; speedup vs baseline: 1.1925x; 1.1925x over previous
//
#include <hip/hip_runtime.h>

#define Tn 512
#define Hn 1024
#define Fn 64
#define NTH 512
#define NW (NTH / 64)

#define STEPB (5u * 512u * 16u) /* 40960 B per timestep (5 comps) */
#define MAXTOFF (511u * STEPB)
#define MAXBOFF (511u * 4096u)
#define REC_PASS ((unsigned long long)Tn * STEPB) /* 20.97 MiB per pass */
#define YXE_OFF (2ull * REC_PASS)
#define FLAG_OFF (YXE_OFF + 131072ull)
#define WS_NEED (FLAG_OFF + 64ull)

#define INV2PI 0.15915494309189535f

typedef unsigned u32x4 __attribute__((ext_vector_type(4)));
typedef __fp16 h2 __attribute__((ext_vector_type(2)));

struct QParams {
  const float *x;
  const float *qw0, *qw1, *qw2, *qw3;
  const float *Wy_e, *by_e, *Wf_e, *bf_e, *Wi_e, *bi_e, *Wu_e, *bu_e, *Wo_e, *bo_e;
  const float *Wy_d, *by_d, *Wf_d, *bf_d, *Wi_d, *bi_d, *Wu_d, *bu_d, *Wo_d, *bo_d;
  const float *Wt, *bt;
  float *out;
};

// ---- sync / wait primitives -------------------------------------------------
#define BAR()                                                                  \
  do {                                                                         \
    asm volatile("s_waitcnt lgkmcnt(0)" ::: "memory");                         \
    __builtin_amdgcn_s_barrier();                                              \
    asm volatile("" ::: "memory");                                             \
  } while (0)
#define WAIT_VM(N)                                                             \
  do {                                                                         \
    asm volatile("s_waitcnt vmcnt(" #N ")" ::: "memory");                      \
    __builtin_amdgcn_sched_barrier(0);                                         \
  } while (0)

// ---- DPP / packed helpers ---------------------------------------------------
template <int CTRL, int RM, int BM, bool BC>
__device__ __forceinline__ float dppadd(float x) {
  int t = __builtin_amdgcn_update_dpp(0, __builtin_bit_cast(int, x), CTRL, RM,
                                      BM, BC);
  return x + __builtin_bit_cast(float, t);
}
template <int CTRL>
__device__ __forceinline__ float dppmov(float x) {
  int t = __builtin_amdgcn_update_dpp(0, __builtin_bit_cast(int, x), CTRL, 0xF,
                                      0xF, true);
  return __builtin_bit_cast(float, t);
}
__device__ __forceinline__ float wave_sum63(float x) {
  x = dppadd<0xB1, 0xF, 0xF, true>(x);
  x = dppadd<0x4E, 0xF, 0xF, true>(x);
  x = dppadd<0x141, 0xF, 0xF, true>(x);
  x = dppadd<0x140, 0xF, 0xF, true>(x);
  x = dppadd<0x142, 0xA, 0xF, false>(x);
  x = dppadd<0x143, 0xC, 0xF, false>(x);
  return x; // lane 63 = wave total
}
__device__ __forceinline__ float tanhc(float c) {
  float e = __builtin_amdgcn_exp2f(c * 2.885390081777927f);
  return fmaf(-2.f, __builtin_amdgcn_rcpf(e + 1.f), 1.f);
}
__device__ __forceinline__ h2 pk2(float a, float b) {
  return __builtin_amdgcn_cvt_pkrtz(a, b);
}
__device__ __forceinline__ h2 uh(unsigned u) { return __builtin_bit_cast(h2, u); }
__device__ __forceinline__ float fdot2f(h2 a, h2 b, float c) {
#if __has_builtin(__builtin_amdgcn_fdot2)
  return __builtin_amdgcn_fdot2(a, b, c, false);
#else
  float d;
  asm("v_dot2_f32_f16 %0, %1, %2, %3" : "=v"(d) : "v"(a), "v"(b), "v"(c));
  return d;
#endif
}
__device__ __forceinline__ float cosrev(float x) { // cos(2*pi*x)
#if __has_builtin(__builtin_amdgcn_cosf)
  return __builtin_amdgcn_cosf(x);
#else
  return __cosf(x * 6.283185307179586f);
#endif
}
__device__ __forceinline__ unsigned pkh(float a, float b) { // RNE pack (prep)
  h2 h;
  h.x = (__fp16)a;
  h.y = (__fp16)b;
  return __builtin_bit_cast(unsigned, h);
}

struct LaneCtx {
  int tid, lane, wid;
  unsigned jt16, jt4;
  bool q1, q2;
  float mlane, alane, klane;
};
struct SBase {
  unsigned long long a[5];
};
struct BBase {
  unsigned long long b[4];
};

// =============================================================================
// flag zeroing (runs before prep; prep atomicOr's into it)
// =============================================================================
__global__ void qflag0_kernel(char *ws) { *(int *)(ws + FLAG_OFF) = 0; }

// =============================================================================
// Pre-pass: f16 records, ws[pass][t][comp(5)][j(512)] u32x4.
//   comp g in 0..3 (f,i,u,o): { h2(Wg[t][0][j],Wg[t][1][j]),
//                               h2(Wg[t][2][j],Wg[t][3][j]),
//                               h2(... j+512 ...), h2(... j+512 ...) }
//   comp 4: { h2(Wy[j][q],Wy[j+512][q])*INV2PI for q=0..3 }  (revolutions)
// Bias handling: records carry NO biases. Prep ORs (bias != 0) into the ws
// flag; the scan kernel's BIASED path loads biases from the original f32
// arrays. Encoder also emits yx[b][t][4] f32 = x@Wy_e[t,1024:,:] + by_e[t].
// =============================================================================
__global__ __launch_bounds__(512) void qprep_kernel(QParams p, char *ws) {
  int t = blockIdx.x;
  const bool dec = (t >= 512);
  if (dec) t -= 512;
  const int j = threadIdx.x;

  const float *Wg0 = dec ? p.Wf_d : p.Wf_e, *Wg1 = dec ? p.Wi_d : p.Wi_e;
  const float *Wg2 = dec ? p.Wu_d : p.Wu_e, *Wg3 = dec ? p.Wo_d : p.Wo_e;
  const float *bf = dec ? p.bf_d : p.bf_e, *bi = dec ? p.bi_d : p.bi_e;
  const float *bu = dec ? p.bu_d : p.bu_e, *bo = dec ? p.bo_d : p.bo_e;
  const float *Wy = dec ? p.Wy_d : p.Wy_e;
  const int K = dec ? (Hn + 1) : (Hn + Fn);

  char *base = ws + (dec ? REC_PASS : 0) + (size_t)t * STEPB;
  const int t4 = t * 4096;
  const float *Wg[4] = {Wg0, Wg1, Wg2, Wg3};
#pragma unroll
  for (int g = 0; g < 4; ++g) {
    u32x4 v;
    v.x = pkh(Wg[g][t4 + 0 * 1024 + j], Wg[g][t4 + 1 * 1024 + j]);
    v.y = pkh(Wg[g][t4 + 2 * 1024 + j], Wg[g][t4 + 3 * 1024 + j]);
    v.z = pkh(Wg[g][t4 + 0 * 1024 + j + 512], Wg[g][t4 + 1 * 1024 + j + 512]);
    v.w = pkh(Wg[g][t4 + 2 * 1024 + j + 512], Wg[g][t4 + 3 * 1024 + j + 512]);
    *(u32x4 *)(base + g * 8192 + j * 16) = v;
  }
  {
    const float4 w0 = *(const float4 *)(Wy + ((size_t)t * K + j) * 4);
    const float4 w1 = *(const float4 *)(Wy + ((size_t)t * K + j + 512) * 4);
    u32x4 v = {pkh(w0.x * INV2PI, w1.x * INV2PI),
               pkh(w0.y * INV2PI, w1.y * INV2PI),
               pkh(w0.z * INV2PI, w1.z * INV2PI),
               pkh(w0.w * INV2PI, w1.w * INV2PI)};
    *(u32x4 *)(base + 4 * 8192 + j * 16) = v;
  }
  { // bias nonzero detection -> ws flag
    const int tb = t * 1024 + j;
    const float s0 = bf[tb], s1 = bf[tb + 512];
    const float s2 = bi[tb], s3 = bi[tb + 512];
    const float s4 = bu[tb], s5 = bu[tb + 512];
    const float s6 = bo[tb], s7 = bo[tb + 512];
    if (s0 != 0.f || s1 != 0.f || s2 != 0.f || s3 != 0.f || s4 != 0.f ||
        s5 != 0.f || s6 != 0.f || s7 != 0.f)
      atomicOr((int *)(ws + FLAG_OFF), 1);
  }

  if (!dec && j < 16) { // yx[b][t] = x(b,t,:)@Wy_e[t,1024:,:] + by_e[t]
    const int b = j;
    float a0 = p.by_e[t * 4 + 0], a1 = p.by_e[t * 4 + 1],
          a2 = p.by_e[t * 4 + 2], a3 = p.by_e[t * 4 + 3];
#pragma unroll 8
    for (int k = 0; k < 64; ++k) {
      const float xv = p.x[((size_t)b * Tn + t) * Fn + k];
      const float4 wr =
          *(const float4 *)(p.Wy_e + ((size_t)t * (Hn + Fn) + Hn + k) * 4);
      a0 = fmaf(xv, wr.x, a0);
      a1 = fmaf(xv, wr.y, a1);
      a2 = fmaf(xv, wr.z, a2);
      a3 = fmaf(xv, wr.w, a3);
    }
    ((float4 *)(ws + YXE_OFF))[(size_t)b * Tn + t] =
        make_float4(a0, a1, a2, a3);
  }
}

// =============================================================================
// Main f16 scan kernel: R8 structure; 5-comp records (no biases), w4 folded
// into the angle table (revolutions), v_cos direct. BIASED template path
// loads f32 biases from the original arrays (only taken if any bias != 0).
// =============================================================================
struct Regs {
  u32x4 c0, c1, c2, c3; // gates f,i,u,o
  u32x4 c4;             // wy (pre-scaled)
  float bf0, bf1, bi0, bi1, bu0, bu1, bo0, bo1; // BIASED only
};

template <bool BIASED>
__device__ __forceinline__ void issue_pf(Regs &r, const SBase &sb,
                                         unsigned voff, const BBase &bb,
                                         unsigned voffB) {
  asm volatile("global_load_dwordx4 %0, %1, %2" : "=v"(r.c4) : "v"(voff), "s"(sb.a[4]));
  asm volatile("global_load_dwordx4 %0, %1, %2" : "=v"(r.c0) : "v"(voff), "s"(sb.a[0]));
  asm volatile("global_load_dwordx4 %0, %1, %2" : "=v"(r.c1) : "v"(voff), "s"(sb.a[1]));
  asm volatile("global_load_dwordx4 %0, %1, %2" : "=v"(r.c2) : "v"(voff), "s"(sb.a[2]));
  asm volatile("global_load_dwordx4 %0, %1, %2" : "=v"(r.c3) : "v"(voff), "s"(sb.a[3]));
  if (BIASED) {
    asm volatile("global_load_dword %0, %1, %2" : "=v"(r.bf0) : "v"(voffB), "s"(bb.b[0]));
    asm volatile("global_load_dword %0, %1, %2 offset:2048" : "=v"(r.bf1) : "v"(voffB), "s"(bb.b[0]));
    asm volatile("global_load_dword %0, %1, %2" : "=v"(r.bi0) : "v"(voffB), "s"(bb.b[1]));
    asm volatile("global_load_dword %0, %1, %2 offset:2048" : "=v"(r.bi1) : "v"(voffB), "s"(bb.b[1]));
    asm volatile("global_load_dword %0, %1, %2" : "=v"(r.bu0) : "v"(voffB), "s"(bb.b[2]));
    asm volatile("global_load_dword %0, %1, %2 offset:2048" : "=v"(r.bu1) : "v"(voffB), "s"(bb.b[2]));
    asm volatile("global_load_dword %0, %1, %2" : "=v"(r.bo0) : "v"(voffB), "s"(bb.b[3]));
    asm volatile("global_load_dword %0, %1, %2 offset:2048" : "=v"(r.bo1) : "v"(voffB), "s"(bb.b[3]));
  }
}

template <int PAR, bool BIASED>
__device__ __forceinline__ void
qstep(int t, Regs &r, unsigned &toff, unsigned &toffB, const SBase &sb,
      const BBase &bb, const LaneCtx &L, float *red_t, const float *yxw_l,
      float &h0, float &h1, float &c0, float &c1, h2 &hp) {
  // angle table read (constant LDS region), hidden under phase A
  const float yxw = yxw_l[t * 16 + (L.lane & 15)];
  if (BIASED) {
    WAIT_VM(39);
  } else {
    WAIT_VM(15);
  }
  // ---------- phase A: y partials (revolutions) via dot2, DPP wave reduce
  float a0 = fdot2f(hp, uh(r.c4.x), 0.f);
  float a1 = fdot2f(hp, uh(r.c4.y), 0.f);
  float a2 = fdot2f(hp, uh(r.c4.z), 0.f);
  float a3 = fdot2f(hp, uh(r.c4.w), 0.f);
  a0 = wave_sum63(a0);
  a1 = wave_sum63(a1);
  a2 = wave_sum63(a2);
  a3 = wave_sum63(a3);
  if (L.lane == 63) {
    red_t[PAR * 32 + 0 * 8 + L.wid] = a0;
    red_t[PAR * 32 + 1 * 8 + L.wid] = a1;
    red_t[PAR * 32 + 2 * 8 + L.wid] = a2;
    red_t[PAR * 32 + 3 * 8 + L.wid] = a3;
  }
  BAR();
  // ---------- phase B: lane sums only its own q = lane&3; circuit
  const float4 rA = *(const float4 *)&red_t[PAR * 32 + (L.lane & 3) * 8 + 0];
  const float4 rB = *(const float4 *)&red_t[PAR * 32 + (L.lane & 3) * 8 + 4];
  const float yq =
      ((rA.x + rA.y) + (rA.z + rA.w)) + ((rB.x + rB.y) + (rB.z + rB.w));
  const float cc = cosrev(yq + yxw); // both in revolutions
  const float t1 = dppmov<0xB1>(cc);
  const float d1 = cc * t1;
  const float t2 = dppmov<0x4E>(d1);
  const float d2 = d1 * t2;
  const float zu = t1 * t2;
  const float zv = cc * t2;
  const float z = L.q2 ? (L.q1 ? d2 : zv) : (L.q1 ? d1 : zu);
  const float s =
      __builtin_amdgcn_rcpf(1.f + __builtin_amdgcn_exp2f(L.klane * z));
  const float act = fmaf(s, L.mlane, L.alane);
  const float actn = dppmov<0xB1>(act);
  const unsigned apk = __builtin_bit_cast(unsigned, pk2(act, actn));
  const h2 F01 = uh((unsigned)__builtin_amdgcn_readlane(apk, 0));
  const h2 F23 = uh((unsigned)__builtin_amdgcn_readlane(apk, 2));
  const h2 I01 = uh((unsigned)__builtin_amdgcn_readlane(apk, 4));
  const h2 I23 = uh((unsigned)__builtin_amdgcn_readlane(apk, 6));
  const h2 U01 = uh((unsigned)__builtin_amdgcn_readlane(apk, 8));
  const h2 U23 = uh((unsigned)__builtin_amdgcn_readlane(apk, 10));
  const h2 O01 = uh((unsigned)__builtin_amdgcn_readlane(apk, 12));
  const h2 O23 = uh((unsigned)__builtin_amdgcn_readlane(apk, 14));
  // ---------- phase C: gate dot2 matvecs (f32 accum) + state update
  const float iF0 = BIASED ? r.bf0 : 0.f, iF1 = BIASED ? r.bf1 : 0.f;
  const float iI0 = BIASED ? r.bi0 : 0.f, iI1 = BIASED ? r.bi1 : 0.f;
  const float iU0 = BIASED ? r.bu0 : 0.f, iU1 = BIASED ? r.bu1 : 0.f;
  const float iO0 = BIASED ? r.bo0 : 0.f, iO1 = BIASED ? r.bo1 : 0.f;
  const float fv0 = fdot2f(F01, uh(r.c0.x), fdot2f(F23, uh(r.c0.y), iF0));
  const float fv1 = fdot2f(F01, uh(r.c0.z), fdot2f(F23, uh(r.c0.w), iF1));
  const float iv0 = fdot2f(I01, uh(r.c1.x), fdot2f(I23, uh(r.c1.y), iI0));
  const float iv1 = fdot2f(I01, uh(r.c1.z), fdot2f(I23, uh(r.c1.w), iI1));
  const float uv0 = fdot2f(U01, uh(r.c2.x), fdot2f(U23, uh(r.c2.y), iU0));
  const float uv1 = fdot2f(U01, uh(r.c2.z), fdot2f(U23, uh(r.c2.w), iU1));
  const float ov0 = fdot2f(O01, uh(r.c3.x), fdot2f(O23, uh(r.c3.y), iO0));
  const float ov1 = fdot2f(O01, uh(r.c3.z), fdot2f(O23, uh(r.c3.w), iO1));
  c0 = fmaf(fv0, c0, iv0 * uv0);
  h0 = ov0 * tanhc(c0);
  c1 = fmaf(fv1, c1, iv1 * uv1);
  h1 = ov1 * tanhc(c1);
  hp = pk2(h0, h1);
  // ---------- reissue this buffer for t+4 (clamped at the tail)
  issue_pf<BIASED>(r, sb, L.jt16 + toff, bb, L.jt4 + toffB);
  toff = toff + STEPB;
  if (toff > MAXTOFF) toff = MAXTOFF;
  if (BIASED) {
    toffB = toffB + 4096u;
    if (toffB > MAXBOFF) toffB = MAXBOFF;
  }
}

template <bool BIASED>
__device__ __forceinline__ void run_pass(const SBase &sb, const BBase &bb,
                                         const LaneCtx &L, float *red_t,
                                         const float *yxw_l, float &h0,
                                         float &h1, float &c0, float &c1) {
  Regs R0, R1, R2, R3;
  WAIT_VM(0);
  issue_pf<BIASED>(R0, sb, L.jt16 + 0 * STEPB, bb, L.jt4 + 0 * 4096u);
  issue_pf<BIASED>(R1, sb, L.jt16 + 1 * STEPB, bb, L.jt4 + 1 * 4096u);
  issue_pf<BIASED>(R2, sb, L.jt16 + 2 * STEPB, bb, L.jt4 + 2 * 4096u);
  issue_pf<BIASED>(R3, sb, L.jt16 + 3 * STEPB, bb, L.jt4 + 3 * 4096u);
  unsigned toff = 4 * STEPB, toffB = 4 * 4096u;
  h2 hp = pk2(0.f, 0.f);
  for (int t = 0; t < Tn; t += 4) {
    qstep<0, BIASED>(t + 0, R0, toff, toffB, sb, bb, L, red_t, yxw_l, h0, h1, c0, c1, hp);
    qstep<1, BIASED>(t + 1, R1, toff, toffB, sb, bb, L, red_t, yxw_l, h0, h1, c0, c1, hp);
    qstep<0, BIASED>(t + 2, R2, toff, toffB, sb, bb, L, red_t, yxw_l, h0, h1, c0, c1, hp);
    qstep<1, BIASED>(t + 3, R3, toff, toffB, sb, bb, L, red_t, yxw_l, h0, h1, c0, c1, hp);
  }
  asm volatile("s_waitcnt vmcnt(0)" ::: "memory");
  __builtin_amdgcn_sched_barrier(0);
}

__global__ __launch_bounds__(NTH, 2) void qlstm_f16_kernel(QParams p,
                                                           char *ws) {
  const int b = blockIdx.x;
  LaneCtx L;
  L.tid = threadIdx.x;
  L.lane = L.tid & 63;
  L.wid = L.tid >> 6;
  L.jt16 = (unsigned)L.tid * 16u;
  L.jt4 = (unsigned)L.tid * 4u;
  const int q = L.lane & 3, g = (L.lane >> 2) & 3;
  L.q1 = q & 1;
  L.q2 = q & 2;
  L.mlane = (g == 2) ? 2.f : 1.f;
  L.alane = 1.f - L.mlane;
  L.klane = -L.mlane * 1.4426950408889634f;

  __shared__ __align__(16) float red_t[2 * 4 * 8];
  __shared__ __align__(16) float yxw_l[Tn * 16]; // 32 KiB: [t][g][q], revs
  __shared__ __align__(16) float hbuf[Hn];

  const int biased = *(volatile const int *)(ws + FLAG_OFF);

  SBase sbE, sbD;
#pragma unroll
  for (int k = 0; k < 5; ++k) {
    sbE.a[k] = (unsigned long long)ws + (unsigned long long)k * 8192ull;
    sbD.a[k] = (unsigned long long)ws + REC_PASS + (unsigned long long)k * 8192ull;
  }
  BBase bbE, bbD;
  bbE.b[0] = (unsigned long long)p.bf_e;
  bbE.b[1] = (unsigned long long)p.bi_e;
  bbE.b[2] = (unsigned long long)p.bu_e;
  bbE.b[3] = (unsigned long long)p.bo_e;
  bbD.b[0] = (unsigned long long)p.bf_d;
  bbD.b[1] = (unsigned long long)p.bi_d;
  bbD.b[2] = (unsigned long long)p.bu_d;
  bbD.b[3] = (unsigned long long)p.bo_d;

  // w4 tables (pre-scaled to revolutions)
  float4 w4r[4];
  {
    const float *qwp[4] = {p.qw0, p.qw1, p.qw2, p.qw3};
#pragma unroll
    for (int gg = 0; gg < 4; ++gg) {
      const float4 w = *(const float4 *)qwp[gg];
      w4r[gg] = make_float4(w.x * INV2PI, w.y * INV2PI, w.z * INV2PI,
                            w.w * INV2PI);
    }
  }

  // ---- encoder prologue: stage angle table yxw[t][g][q] (revolutions)
  {
    const float4 yx4 =
        ((const float4 *)(ws + YXE_OFF))[(size_t)b * Tn + L.tid];
#pragma unroll
    for (int gg = 0; gg < 4; ++gg) {
      ((float4 *)yxw_l)[L.tid * 4 + gg] =
          make_float4(fmaf(yx4.x, INV2PI, w4r[gg].x),
                      fmaf(yx4.y, INV2PI, w4r[gg].y),
                      fmaf(yx4.z, INV2PI, w4r[gg].z),
                      fmaf(yx4.w, INV2PI, w4r[gg].w));
    }
  }
  float h0 = 0.f, h1 = 0.f, c0 = 0.f, c1 = 0.f;
  __syncthreads();

  if (biased)
    run_pass<true>(sbE, bbE, L, red_t, yxw_l, h0, h1, c0, c1);
  else
    run_pass<false>(sbE, bbE, L, red_t, yxw_l, h0, h1, c0, c1);

  // ---- transition: stage h_enc, rebuild angle table for decoder
  __syncthreads();
  hbuf[L.tid] = h0;
  hbuf[L.tid + NTH] = h1;
  __syncthreads();
  {
    const float hv = hbuf[L.tid]; // = h_enc[t] for t = tid
    const float4 wx =
        *(const float4 *)(p.Wy_d + ((size_t)L.tid * (Hn + 1) + Hn) * 4);
    const float4 bd = *(const float4 *)(p.by_d + L.tid * 4);
    const float bx = fmaf(hv, wx.x, bd.x) * INV2PI;
    const float by2 = fmaf(hv, wx.y, bd.y) * INV2PI;
    const float bz = fmaf(hv, wx.z, bd.z) * INV2PI;
    const float bw = fmaf(hv, wx.w, bd.w) * INV2PI;
#pragma unroll
    for (int gg = 0; gg < 4; ++gg) {
      ((float4 *)yxw_l)[L.tid * 4 + gg] =
          make_float4(bx + w4r[gg].x, by2 + w4r[gg].y, bz + w4r[gg].z,
                      bw + w4r[gg].w);
    }
  }
  h0 = h1 = c0 = c1 = 0.f;
  __syncthreads();

  if (biased)
    run_pass<true>(sbD, bbD, L, red_t, yxw_l, h0, h1, c0, c1);
  else
    run_pass<false>(sbD, bbD, L, red_t, yxw_l, h0, h1, c0, c1);

  // ---- projection: out[b][t] = h_dec @ Wt[:,t] + bt[t]
  __syncthreads();
  hbuf[L.tid] = h0;
  hbuf[L.tid + NTH] = h1;
  __syncthreads();
  {
    float acc = p.bt[L.tid];
    const float4 *h4 = (const float4 *)hbuf;
#pragma unroll 4
    for (int j4 = 0; j4 < Hn / 4; ++j4) {
      const float4 hv = h4[j4];
      acc = fmaf(hv.x, p.Wt[(j4 * 4 + 0) * Tn + L.tid], acc);
      acc = fmaf(hv.y, p.Wt[(j4 * 4 + 1) * Tn + L.tid], acc);
      acc = fmaf(hv.z, p.Wt[(j4 * 4 + 2) * Tn + L.tid], acc);
      acc = fmaf(hv.w, p.Wt[(j4 * 4 + 3) * Tn + L.tid], acc);
    }
    p.out[(size_t)b * Tn + L.tid] = acc;
  }
}

// =============================================================================
// Fallback (round-3 f32 kernel): used only if ws_size < WS_NEED.
// =============================================================================
#define FNTH 512
#define FNW (FNTH / 64)
__device__ __forceinline__ float sum8_all(float x) {
  x = dppadd<0xB1, 0xF, 0xF, true>(x);
  x = dppadd<0x4E, 0xF, 0xF, true>(x);
  x = dppadd<0x141, 0xF, 0xF, true>(x);
  return x;
}

struct WB {
  float w[32];
  float bb[8];
  float4 wy0, wy1;
  float4 wyx;
  float xv;
};

template <bool DEC>
__device__ __forceinline__ WB
pf_fb(int t, int b, int tid, const float *__restrict__ x,
      const float *__restrict__ Wy, const float *__restrict__ Wf,
      const float *__restrict__ bfp, const float *__restrict__ Wi,
      const float *__restrict__ bip, const float *__restrict__ Wu,
      const float *__restrict__ bup, const float *__restrict__ Wo,
      const float *__restrict__ bop) {
  WB d;
  const int K = DEC ? (Hn + 1) : (Hn + Fn);
  const int g0 = t * 4096 + tid;
#pragma unroll
  for (int e = 0; e < 2; ++e) {
    const int ge = g0 + e * 512;
#pragma unroll
    for (int n = 0; n < 4; ++n) {
      d.w[e * 16 + 0 * 4 + n] = Wf[ge + n * 1024];
      d.w[e * 16 + 1 * 4 + n] = Wi[ge + n * 1024];
      d.w[e * 16 + 2 * 4 + n] = Wu[ge + n * 1024];
      d.w[e * 16 + 3 * 4 + n] = Wo[ge + n * 1024];
    }
    const int be = t * 1024 + tid + e * 512;
    d.bb[e * 4 + 0] = bfp[be];
    d.bb[e * 4 + 1] = bip[be];
    d.bb[e * 4 + 2] = bup[be];
    d.bb[e * 4 + 3] = bop[be];
  }
  d.wy0 = *(const float4 *)(Wy + (t * K + tid) * 4);
  d.wy1 = *(const float4 *)(Wy + (t * K + tid + 512) * 4);
  if (!DEC) {
    if (tid < Fn) {
      d.wyx = *(const float4 *)(Wy + (t * K + Hn + tid) * 4);
      d.xv = x[(b * Tn + t) * Fn + tid];
    }
  } else {
    if (tid == 0) d.wyx = *(const float4 *)(Wy + (t * K + Hn) * 4);
  }
  return d;
}

struct FLane {
  int tid, lane, wid;
  bool q1, q2;
  float w4lane, mlane, alane, klane;
};

template <bool DEC, int PAR>
__device__ __forceinline__ void
step_fb(int t, int tn, const WB &rd, WB &wr, int b, const FLane &L,
        const float *__restrict__ x, const float *__restrict__ Wy,
        const float *__restrict__ Wf, const float *__restrict__ bfp,
        const float *__restrict__ Wi, const float *__restrict__ bip,
        const float *__restrict__ Wu, const float *__restrict__ bup,
        const float *__restrict__ Wo, const float *__restrict__ bop,
        float4 (*red4)[FNW], const float *by_l, const float *henc_s, float &h0,
        float &h1, float &c0, float &c1) {
  float a0 = h0 * rd.wy0.x, a1 = h0 * rd.wy0.y, a2 = h0 * rd.wy0.z,
        a3 = h0 * rd.wy0.w;
  a0 = fmaf(h1, rd.wy1.x, a0);
  a1 = fmaf(h1, rd.wy1.y, a1);
  a2 = fmaf(h1, rd.wy1.z, a2);
  a3 = fmaf(h1, rd.wy1.w, a3);
  if (!DEC) {
    if (L.tid < Fn) {
      a0 = fmaf(rd.xv, rd.wyx.x, a0);
      a1 = fmaf(rd.xv, rd.wyx.y, a1);
      a2 = fmaf(rd.xv, rd.wyx.z, a2);
      a3 = fmaf(rd.xv, rd.wyx.w, a3);
    }
  } else {
    if (L.tid == 0) {
      const float xv = henc_s[t];
      a0 = fmaf(xv, rd.wyx.x, a0);
      a1 = fmaf(xv, rd.wyx.y, a1);
      a2 = fmaf(xv, rd.wyx.z, a2);
      a3 = fmaf(xv, rd.wyx.w, a3);
    }
  }
  a0 = wave_sum63(a0);
  a1 = wave_sum63(a1);
  a2 = wave_sum63(a2);
  a3 = wave_sum63(a3);
  if (L.lane == 63) red4[PAR][L.wid] = make_float4(a0, a1, a2, a3);
  wr = pf_fb<DEC>(tn, b, L.tid, x, Wy, Wf, bfp, Wi, bip, Wu, bup, Wo, bop);
  BAR();
  float4 rv = red4[PAR][L.lane & 7];
  const float byq = by_l[t * 4 + (L.lane & 3)];
  float y0 = sum8_all(rv.x), y1 = sum8_all(rv.y), y2 = sum8_all(rv.z),
        y3 = sum8_all(rv.w);
  const float yq = L.q2 ? (L.q1 ? y3 : y2) : (L.q1 ? y1 : y0);
  const float ang = yq + byq + L.w4lane;
  const float cc = __cosf(ang);
  const float t1 = dppmov<0xB1>(cc);
  const float d1 = cc * t1;
  const float t2 = dppmov<0x4E>(d1);
  const float d2 = d1 * t2;
  const float zu = t1 * t2;
  const float zv = cc * t2;
  const float z = L.q2 ? (L.q1 ? d2 : zv) : (L.q1 ? d1 : zu);
  const float s =
      __builtin_amdgcn_rcpf(1.f + __builtin_amdgcn_exp2f(L.klane * z));
  const float act = fmaf(s, L.mlane, L.alane);
#define RL(n)                                                                  \
  __builtin_bit_cast(float,                                                    \
                     __builtin_amdgcn_readlane(__builtin_bit_cast(int, act), n))
  const float f0 = RL(0), f1 = RL(1), f2 = RL(2), f3 = RL(3);
  const float i0 = RL(4), i1 = RL(5), i2 = RL(6), i3 = RL(7);
  const float u0 = RL(8), u1 = RL(9), u2 = RL(10), u3 = RL(11);
  const float o0 = RL(12), o1 = RL(13), o2 = RL(14), o3 = RL(15);
#undef RL
#pragma unroll
  for (int e = 0; e < 2; ++e) {
    float fv = rd.bb[e * 4 + 0], iv = rd.bb[e * 4 + 1], uv = rd.bb[e * 4 + 2],
          ov = rd.bb[e * 4 + 3];
    fv = fmaf(f0, rd.w[e * 16 + 0], fv);
    fv = fmaf(f1, rd.w[e * 16 + 1], fv);
    fv = fmaf(f2, rd.w[e * 16 + 2], fv);
    fv = fmaf(f3, rd.w[e * 16 + 3], fv);
    iv = fmaf(i0, rd.w[e * 16 + 4], iv);
    iv = fmaf(i1, rd.w[e * 16 + 5], iv);
    iv = fmaf(i2, rd.w[e * 16 + 6], iv);
    iv = fmaf(i3, rd.w[e * 16 + 7], iv);
    uv = fmaf(u0, rd.w[e * 16 + 8], uv);
    uv = fmaf(u1, rd.w[e * 16 + 9], uv);
    uv = fmaf(u2, rd.w[e * 16 + 10], uv);
    uv = fmaf(u3, rd.w[e * 16 + 11], uv);
    ov = fmaf(o0, rd.w[e * 16 + 12], ov);
    ov = fmaf(o1, rd.w[e * 16 + 13], ov);
    ov = fmaf(o2, rd.w[e * 16 + 14], ov);
    ov = fmaf(o3, rd.w[e * 16 + 15], ov);
    float &cr = e ? c1 : c0;
    float &hr = e ? h1 : h0;
    const float cn = fmaf(fv, cr, iv * uv);
    cr = cn;
    hr = ov * tanhc(cn);
  }
}

template <bool DEC>
__device__ void lstm_pass_fb(int b, const FLane &L,
                             const float *__restrict__ x,
                             const float *__restrict__ Wy,
                             const float *__restrict__ by,
                             const float *__restrict__ Wf,
                             const float *__restrict__ bfp,
                             const float *__restrict__ Wi,
                             const float *__restrict__ bip,
                             const float *__restrict__ Wu,
                             const float *__restrict__ bup,
                             const float *__restrict__ Wo,
                             const float *__restrict__ bop,
                             float4 (*red4)[FNW], float *by_l,
                             const float *henc_s, float &h0, float &h1,
                             float &c0, float &c1) {
#pragma unroll
  for (int i = 0; i < (Tn * 4) / FNTH; ++i)
    by_l[L.tid + i * FNTH] = by[L.tid + i * FNTH];
  __syncthreads();
  WB bufA = pf_fb<DEC>(0, b, L.tid, x, Wy, Wf, bfp, Wi, bip, Wu, bup, Wo, bop);
  WB bufB;
  for (int t = 0; t < Tn; t += 2) {
    step_fb<DEC, 0>(t, t + 1, bufA, bufB, b, L, x, Wy, Wf, bfp, Wi, bip, Wu,
                    bup, Wo, bop, red4, by_l, henc_s, h0, h1, c0, c1);
    step_fb<DEC, 1>(t + 1, (t + 2 < Tn) ? (t + 2) : (Tn - 1), bufB, bufA, b, L,
                    x, Wy, Wf, bfp, Wi, bip, Wu, bup, Wo, bop, red4, by_l,
                    henc_s, h0, h1, c0, c1);
  }
}

__global__ __launch_bounds__(FNTH, 2) void qlstm_fb_kernel(QParams p) {
  const int b = blockIdx.x;
  FLane L;
  L.tid = threadIdx.x;
  L.lane = L.tid & 63;
  L.wid = L.tid >> 6;
  const int q = L.lane & 3, g = (L.lane >> 2) & 3;
  L.q1 = q & 1;
  L.q2 = q & 2;
  {
    const float *qwp =
        (g == 0) ? p.qw0 : (g == 1) ? p.qw1 : (g == 2) ? p.qw2 : p.qw3;
    L.w4lane = qwp[q];
  }
  L.mlane = (g == 2) ? 2.f : 1.f;
  L.alane = 1.f - L.mlane;
  L.klane = -L.mlane * 1.4426950408889634f;

  __shared__ float4 red4[2][FNW];
  __shared__ float by_l[Tn * 4];
  __shared__ float henc_s[Hn];
  __shared__ float hst[Hn];

  float h0 = 0.f, h1 = 0.f, c0 = 0.f, c1 = 0.f;

  lstm_pass_fb<false>(b, L, p.x, p.Wy_e, p.by_e, p.Wf_e, p.bf_e, p.Wi_e,
                      p.bi_e, p.Wu_e, p.bu_e, p.Wo_e, p.bo_e, red4, by_l,
                      henc_s, h0, h1, c0, c1);
  henc_s[L.tid] = h0;
  henc_s[L.tid + FNTH] = h1;
  h0 = h1 = c0 = c1 = 0.f;
  __syncthreads();
  lstm_pass_fb<true>(b, L, nullptr, p.Wy_d, p.by_d, p.Wf_d, p.bf_d, p.Wi_d,
                     p.bi_d, p.Wu_d, p.bu_d, p.Wo_d, p.bo_d, red4, by_l,
                     henc_s, h0, h1, c0, c1);
  hst[L.tid] = h0;
  hst[L.tid + FNTH] = h1;
  __syncthreads();
  {
    float acc = p.bt[L.tid];
    const float4 *h4 = (const float4 *)hst;
#pragma unroll 4
    for (int j4 = 0; j4 < Hn / 4; ++j4) {
      const float4 hv = h4[j4];
      acc = fmaf(hv.x, p.Wt[(j4 * 4 + 0) * Tn + L.tid], acc);
      acc = fmaf(hv.y, p.Wt[(j4 * 4 + 1) * Tn + L.tid], acc);
      acc = fmaf(hv.z, p.Wt[(j4 * 4 + 2) * Tn + L.tid], acc);
      acc = fmaf(hv.w, p.Wt[(j4 * 4 + 3) * Tn + L.tid], acc);
    }
    p.out[(size_t)b * Tn + L.tid] = acc;
  }
}

extern "C" void kernel_launch(void *const *d_in, const int *in_sizes, int n_in,
                              void *d_out, int out_size, void *d_ws,
                              size_t ws_size, hipStream_t stream) {
  QParams p;
  p.x = (const float *)d_in[0];
  p.qw0 = (const float *)d_in[1];
  p.qw1 = (const float *)d_in[2];
  p.qw2 = (const float *)d_in[3];
  p.qw3 = (const float *)d_in[4];
  p.Wy_e = (const float *)d_in[5];
  p.by_e = (const float *)d_in[6];
  p.Wf_e = (const float *)d_in[7];
  p.bf_e = (const float *)d_in[8];
  p.Wi_e = (const float *)d_in[9];
  p.bi_e = (const float *)d_in[10];
  p.Wu_e = (const float *)d_in[11];
  p.bu_e = (const float *)d_in[12];
  p.Wo_e = (const float *)d_in[13];
  p.bo_e = (const float *)d_in[14];
  p.Wy_d = (const float *)d_in[15];
  p.by_d = (const float *)d_in[16];
  p.Wf_d = (const float *)d_in[17];
  p.bf_d = (const float *)d_in[18];
  p.Wi_d = (const float *)d_in[19];
  p.bi_d = (const float *)d_in[20];
  p.Wu_d = (const float *)d_in[21];
  p.bu_d = (const float *)d_in[22];
  p.Wo_d = (const float *)d_in[23];
  p.bo_d = (const float *)d_in[24];
  p.Wt = (const float *)d_in[25];
  p.bt = (const float *)d_in[26];
  p.out = (float *)d_out;

  if (ws_size >= WS_NEED) {
    char *ws = (char *)d_ws;
    hipLaunchKernelGGL(qflag0_kernel, dim3(1), dim3(1), 0, stream, ws);
    hipLaunchKernelGGL(qprep_kernel, dim3(1024), dim3(512), 0, stream, p, ws);
    hipLaunchKernelGGL(qlstm_f16_kernel, dim3(16), dim3(NTH), 0, stream, p,
                       ws);
  } else {
    hipLaunchKernelGGL(qlstm_fb_kernel, dim3(16), dim3(FNTH), 0, stream, p);
  }
}